// Round 8
// baseline (282.936 us; speedup 1.0000x reference)
//
#include <hip/hip_runtime.h>
#include <hip/hip_bf16.h>

typedef unsigned short u16;
typedef __bf16 bf16x8 __attribute__((ext_vector_type(8)));
typedef float   f32x4 __attribute__((ext_vector_type(4)));
typedef u16     u16x8 __attribute__((ext_vector_type(8)));
typedef u16     u16x4 __attribute__((ext_vector_type(4)));

#define DEV static __device__ __forceinline__

DEV float bf2f(u16 b) { unsigned int u = ((unsigned int)b) << 16; return __builtin_bit_cast(float, u); }
DEV u16   f2bf(float f) { return __builtin_bit_cast(u16, (__bf16)f); }
DEV bf16x8 ldb(const u16* p) { return __builtin_bit_cast(bf16x8, *(const u16x8*)p); }

DEV f32x4 mfma_bf16(bf16x8 a, bf16x8 b, f32x4 c) {
  return __builtin_amdgcn_mfma_f32_16x16x32_bf16(a, b, c, 0, 0, 0);
}

// async global->LDS, 16B per lane. LDS dest must be wave-uniform (HW adds lane*16).
DEV void gl16(const u16* g, u16* l) {
  __builtin_amdgcn_global_load_lds((const __attribute__((address_space(1))) unsigned int*)g,
                                   (__attribute__((address_space(3))) unsigned int*)l,
                                   16, 0, 0);
}

#define BAR_VM0()  asm volatile("s_waitcnt vmcnt(0)\ns_barrier" ::: "memory")
#define BAR_FULL() asm volatile("s_waitcnt vmcnt(0) lgkmcnt(0)\ns_barrier" ::: "memory")

// ---------------- dtype detection -------------------------------------------
__global__ __launch_bounds__(256) void detect_dtype(const u16* x, int* flag) {
  int tid = threadIdx.x;
  u16 lo = x[tid * 2];
  float v = bf2f(lo);
  float av = fabsf(v);
  bool plaus = (av > 1e-4f && av < 50.f);
  __shared__ int cnt;
  if (tid == 0) cnt = 0;
  __syncthreads();
  if (plaus) atomicAdd(&cnt, 1);
  __syncthreads();
  if (tid == 0) *flag = (cnt >= 128) ? 1 : 0;   // 1 = bf16 inputs
}

// ---------------- input canonicalization to bf16 ------------------------------
struct Cv2 { const void* s[2]; u16* d[2]; };
__global__ __launch_bounds__(256) void convert_big(Cv2 p, const int* flagp) {
  int fl = *flagp;
  const void* src = p.s[blockIdx.z];
  u16* dst = p.d[blockIdx.z];
  size_t i = ((size_t)blockIdx.x * 256 + threadIdx.x) * 8;
  if (fl) {
    *(u16x8*)(dst + i) = *(const u16x8*)((const u16*)src + i);
  } else {
    const float* s = (const float*)src + i;
    u16x8 o;
#pragma unroll
    for (int k = 0; k < 8; ++k) o[k] = f2bf(s[k]);
    *(u16x8*)(dst + i) = o;
  }
}

struct Sm4 { const void* s[4]; u16* d[4]; };
__global__ __launch_bounds__(256) void convert_smalls(Sm4 p, const int* flagp) {
  int fl = *flagp;
  const void* src = p.s[blockIdx.x];
  u16* dst = p.d[blockIdx.x];
  int i = threadIdx.x * 4;
#pragma unroll
  for (int k = 0; k < 4; ++k)
    dst[i + k] = fl ? ((const u16*)src)[i + k] : f2bf(((const float*)src)[i + k]);
}

// ---------------- weight transpose: dst[n][k] = src[k][n], 1024x1024 ---------
struct T6 { const void* s[6]; u16* d[6]; };

__global__ __launch_bounds__(256) void transpose6(T6 t, const int* flagp) {
  int fl = *flagp;
  __shared__ u16 tile[32][33];
  const void* src = t.s[blockIdx.z];
  u16* dst = t.d[blockIdx.z];
  int x0 = blockIdx.x * 32, y0 = blockIdx.y * 32;
  int tx = threadIdx.x & 31, ty = threadIdx.x >> 5;   // 32 x 8
#pragma unroll
  for (int i = 0; i < 32; i += 8) {
    size_t idx = (size_t)(y0 + ty + i) * 1024 + x0 + tx;
    tile[ty + i][tx] = fl ? ((const u16*)src)[idx] : f2bf(((const float*)src)[idx]);
  }
  __syncthreads();
#pragma unroll
  for (int i = 0; i < 32; i += 8)
    dst[(size_t)(x0 + ty + i) * 1024 + y0 + tx] = tile[tx][ty + i];
}

// ---------------- projection GEMM, 256x256 tile / BK=64 / 8 waves ------------
struct Proj4 { const u16* A[4]; const u16* Bt[4]; u16* C[4]; int mode[4]; };

__global__ __launch_bounds__(512, 2) void gemm_proj(Proj4 p) {
  const int K = 1024, Nn = 1024;
  const u16* A  = p.A[blockIdx.z];
  const u16* Bt = p.Bt[blockIdx.z];
  u16* C = p.C[blockIdx.z];
  int mode = p.mode[blockIdx.z];

  __shared__ __align__(16) u16 As[2][256 * 64];
  __shared__ __align__(16) u16 Bs[2][256 * 64];

  int tid = threadIdx.x, lane = tid & 63, w = tid >> 6;
  int wm = w >> 2, wn = w & 3;          // 2 x 4 wave grid, wave tile 128x64
  int q4 = lane >> 4, c = lane & 15;

  // XCD swizzle within slice: 64 wgs, 64%8==0 -> bijective
  int bid = blockIdx.y * 4 + blockIdx.x;
  int wg  = (bid & 7) * 8 + (bid >> 3);
  int m0 = (wg >> 2) * 256, n0 = (wg & 3) * 256;

  int srow = w * 8 + (lane >> 3);
  int scol = ((lane & 7) ^ (lane >> 3)) * 8;
  const u16* pAg = A  + (size_t)(m0 + srow) * K + scol;
  const u16* pBg = Bt + (size_t)(n0 + srow) * K + scol;
  int sdst = (w * 8) * 64;

  int xo0 = ((0 * 4 + q4) ^ (c & 7)) * 8;
  int xo1 = ((1 * 4 + q4) ^ (c & 7)) * 8;

  f32x4 acc[8][4] = {};

#define STAGE256(pb, kt)                                                    \
  { int ko = (kt) * 64;                                                     \
    _Pragma("unroll") for (int s = 0; s < 4; ++s) {                         \
      gl16(pAg + (size_t)s * 64 * 1024 + ko, As[pb] + s * 4096 + sdst);     \
      gl16(pBg + (size_t)s * 64 * 1024 + ko, Bs[pb] + s * 4096 + sdst);     \
    } }

#define COMP256(pb)                                                         \
  { bf16x8 bq[4][2];                                                        \
    _Pragma("unroll") for (int j = 0; j < 4; ++j) {                         \
      int rb = (wn * 64 + j * 16 + c) * 64;                                 \
      bq[j][0] = ldb(Bs[pb] + rb + xo0);                                    \
      bq[j][1] = ldb(Bs[pb] + rb + xo1);                                    \
    }                                                                       \
    _Pragma("unroll") for (int f = 0; f < 4; ++f) {                         \
      bf16x8 aq[2][2];                                                      \
      _Pragma("unroll") for (int ii = 0; ii < 2; ++ii) {                    \
        int ra = (wm * 128 + (f * 2 + ii) * 16 + c) * 64;                   \
        aq[ii][0] = ldb(As[pb] + ra + xo0);                                 \
        aq[ii][1] = ldb(As[pb] + ra + xo1);                                 \
      }                                                                     \
      __builtin_amdgcn_s_setprio(1);                                        \
      _Pragma("unroll") for (int ii = 0; ii < 2; ++ii)                      \
        _Pragma("unroll") for (int j = 0; j < 4; ++j) {                     \
          acc[f*2+ii][j] = mfma_bf16(aq[ii][0], bq[j][0], acc[f*2+ii][j]);  \
          acc[f*2+ii][j] = mfma_bf16(aq[ii][1], bq[j][1], acc[f*2+ii][j]);  \
        }                                                                   \
      __builtin_amdgcn_s_setprio(0);                                        \
    } }

  STAGE256(0, 0);
  BAR_VM0();
  for (int t = 0; t < 16; t += 2) {
    STAGE256(1, t + 1);
    COMP256(0);
    BAR_FULL();
    if (t + 2 < 16) STAGE256(0, t + 2);
    COMP256(1);
    BAR_FULL();
  }
#undef STAGE256
#undef COMP256

  if (mode == 0) {
#pragma unroll
    for (int i = 0; i < 8; ++i) {
      int mrow = m0 + wm * 128 + i * 16 + q4 * 4;
#pragma unroll
      for (int j = 0; j < 4; ++j) {
        int col = n0 + wn * 64 + j * 16 + c;
#pragma unroll
        for (int r = 0; r < 4; ++r)
          C[(size_t)(mrow + r) * Nn + col] = f2bf(acc[i][j][r]);
      }
    }
  } else {
    int bidx = m0 >> 10;
#pragma unroll
    for (int i = 0; i < 8; ++i) {
      int mrow = m0 + wm * 128 + i * 16 + q4 * 4;
      int jj = mrow & 1023;
#pragma unroll
      for (int j = 0; j < 4; ++j) {
        int col = n0 + wn * 64 + j * 16 + c;
        int h = col >> 6, dh = col & 63;
        u16x4 pk;
#pragma unroll
        for (int r = 0; r < 4; ++r) pk[r] = f2bf(acc[i][j][r]);
        *(u16x4*)(C + ((size_t)((bidx * 16 + h) * 64 + dh)) * 1024 + jj) = pk;
      }
    }
  }
}

// ---------------- flash attention (max-free, S^T orientation) ----------------
// 512 blocks, 256 Q-rows per block (4 i-groups per wave): K/V staging, barriers
// and frag reads amortize over 72 MFMA/wave/tile. XCD decode: the 4 i-blocks
// sharing one (bh,z) K/V panel have equal flat%8 -> same XCD L2.
struct FAz { const u16* Q[2]; const u16* Kp[2]; const u16* Vp[2]; u16* O[2]; };

__global__ __launch_bounds__(256) void flash_attn(FAz fa) {
  int flat = blockIdx.x;
  int i0 = (flat >> 7) * 256;
  int grp = flat & 127;
  int z = grp >> 6;
  int bh = grp & 63;
  const u16* Q  = fa.Q[z];
  const u16* Kg = fa.Kp[z];
  const u16* Vt = fa.Vp[z];
  u16* O = fa.O[z];

  int b = bh >> 4, h = bh & 15;
  int tid = threadIdx.x, lane = tid & 63, w = tid >> 6;
  int q4 = lane >> 4, c = lane & 15;

  __shared__ __align__(16) u16 Ks[64 * 64];       // [j][d] chunk-XOR swizzled
  __shared__ __align__(16) u16 Vs[64 * 64];       // [d][j] chunk-XOR swizzled
  __shared__ __align__(16) u16 Ps[4][4][16 * 72]; // per-wave, per-group P [i][j]

  bf16x8 qf[4][2];
#pragma unroll
  for (int g = 0; g < 4; ++g) {
    const size_t qoff = ((size_t)(b * 1024 + i0 + g * 64 + w * 16 + c)) * 1024 + h * 64 + q4 * 8;
    qf[g][0] = ldb(Q + qoff);
    qf[g][1] = ldb(Q + qoff + 32);
  }

  f32x4 of[4][4] = {};
  f32x4 lacc[4] = {};
  bf16x8 ones;
#pragma unroll
  for (int k = 0; k < 8; ++k) ones[k] = (__bf16)1.0f;

  int jr = tid >> 2, seg = (tid & 3) * 16;
  const u16* krow_base = Kg + ((size_t)(b * 1024 + jr)) * 1024 + h * 64 + seg;
  const u16* vrow_base = Vt + ((size_t)((b * 16 + h) * 64 + jr)) * 1024 + seg;

  // swizzled LDS write addresses for this lane's two 16B chunks
  int ch0 = (tid & 3) * 2, jrx = jr & 7;
  int wa0 = jr * 64 + ((ch0)     ^ jrx) * 8;
  int wa1 = jr * 64 + ((ch0 + 1) ^ jrx) * 8;
  // swizzled read offsets (per-thread constants)
  int xA = (q4 ^ (c & 7)) * 8;
  int xB = xA ^ 32;

  const float C2 = 0.125f * 1.4426950408889634f;  // scale * log2(e)

  u16x8 kv0 = *(const u16x8*)(krow_base);
  u16x8 kv1 = *(const u16x8*)(krow_base + 8);
  u16x8 vv0 = *(const u16x8*)(vrow_base);
  u16x8 vv1 = *(const u16x8*)(vrow_base + 8);

  for (int j0 = 0; j0 < 1024; j0 += 64) {
    __syncthreads();
    *(u16x8*)(Ks + wa0) = kv0;
    *(u16x8*)(Ks + wa1) = kv1;
    *(u16x8*)(Vs + wa0) = vv0;
    *(u16x8*)(Vs + wa1) = vv1;
    __syncthreads();

    if (j0 + 64 < 1024) {
      const u16* ks = krow_base + (size_t)(j0 + 64) * 1024;
      kv0 = *(const u16x8*)(ks);
      kv1 = *(const u16x8*)(ks + 8);
      const u16* vs = vrow_base + j0 + 64;
      vv0 = *(const u16x8*)(vs);
      vv1 = *(const u16x8*)(vs + 8);
    }

    // S^T: sf[g][jc][r] = S[i=c (group g)][j = jc*16 + 4*q4 + r]
    f32x4 sf[4][4] = {};
    __builtin_amdgcn_s_setprio(1);
#pragma unroll
    for (int jc = 0; jc < 4; ++jc) {
      int rk = (jc * 16 + c) * 64;
      bf16x8 k0f = ldb(Ks + rk + xA);
      bf16x8 k1f = ldb(Ks + rk + xB);
#pragma unroll
      for (int g = 0; g < 4; ++g) {
        sf[g][jc] = mfma_bf16(k0f, qf[g][0], sf[g][jc]);
        sf[g][jc] = mfma_bf16(k1f, qf[g][1], sf[g][jc]);
      }
    }
    __builtin_amdgcn_s_setprio(0);

#pragma unroll
    for (int g = 0; g < 4; ++g)
#pragma unroll
      for (int jc = 0; jc < 4; ++jc) {
        u16x4 pk;
#pragma unroll
        for (int r = 0; r < 4; ++r)
          pk[r] = f2bf(__builtin_amdgcn_exp2f(sf[g][jc][r] * C2));
        *(u16x4*)(Ps[w][g] + c * 72 + jc * 16 + q4 * 4) = pk;
      }

    asm volatile("s_waitcnt lgkmcnt(0)" ::: "memory");

    bf16x8 pf[4][2];
#pragma unroll
    for (int g = 0; g < 4; ++g) {
      pf[g][0] = ldb(Ps[w][g] + c * 72 + q4 * 8);
      pf[g][1] = ldb(Ps[w][g] + c * 72 + 32 + q4 * 8);
      lacc[g] = mfma_bf16(pf[g][0], ones, lacc[g]);
      lacc[g] = mfma_bf16(pf[g][1], ones, lacc[g]);
    }

    __builtin_amdgcn_s_setprio(1);
#pragma unroll
    for (int dc = 0; dc < 4; ++dc) {
      int rv = (dc * 16 + c) * 64;
      bf16x8 v0f = ldb(Vs + rv + xA);
      bf16x8 v1f = ldb(Vs + rv + xB);
#pragma unroll
      for (int g = 0; g < 4; ++g) {
        of[g][dc] = mfma_bf16(pf[g][0], v0f, of[g][dc]);
        of[g][dc] = mfma_bf16(pf[g][1], v1f, of[g][dc]);
      }
    }
    __builtin_amdgcn_s_setprio(0);
  }

#pragma unroll
  for (int g = 0; g < 4; ++g) {
    float inv[4];
#pragma unroll
    for (int r = 0; r < 4; ++r) inv[r] = 1.0f / lacc[g][r];
#pragma unroll
    for (int dc = 0; dc < 4; ++dc) {
      int col = h * 64 + dc * 16 + c;
#pragma unroll
      for (int r = 0; r < 4; ++r) {
        int irow = i0 + g * 64 + w * 16 + q4 * 4 + r;
        O[((size_t)(b * 1024 + irow)) * 1024 + col] = f2bf(of[g][dc][r] * inv[r]);
      }
    }
  }
}

// ---------------- final dual GEMM + bias -> fp32, 256^2 / BK=64 / 8 waves ----
// Y[m][n] = sum_k A1[m][k]*B1t[n][k] + A2[m][k]*B2t[n][k] + b1[n] + b2[n]
// 32 K-tiles: kt<16 reads (A1,B1) with ko=kt*64 (full K=1024), kt>=16 reads
// (A2,B2) with ko=(kt-16)*64. (Round-7 bug: 16 tiles covered only half of
// each K-range.)
__global__ __launch_bounds__(512, 2) void gemm_final(const u16* A1, const u16* B1t,
                                                     const u16* A2, const u16* B2t,
                                                     const u16* b1, const u16* b2,
                                                     float* Y) {
  const int K = 1024, Nn = 1024;
  __shared__ __align__(16) u16 As[2][256 * 64];
  __shared__ __align__(16) u16 Bs[2][256 * 64];

  int tid = threadIdx.x, lane = tid & 63, w = tid >> 6;
  int wm = w >> 2, wn = w & 3;
  int q4 = lane >> 4, c = lane & 15;

  int bid = blockIdx.y * 4 + blockIdx.x;
  int wg  = (bid & 7) * 8 + (bid >> 3);
  int m0 = (wg >> 2) * 256, n0 = (wg & 3) * 256;

  int srow = w * 8 + (lane >> 3);
  int scol = ((lane & 7) ^ (lane >> 3)) * 8;
  const u16* pA1 = A1  + (size_t)(m0 + srow) * K + scol;
  const u16* pA2 = A2  + (size_t)(m0 + srow) * K + scol;
  const u16* pB1 = B1t + (size_t)(n0 + srow) * K + scol;
  const u16* pB2 = B2t + (size_t)(n0 + srow) * K + scol;
  int sdst = (w * 8) * 64;

  int xo0 = ((0 * 4 + q4) ^ (c & 7)) * 8;
  int xo1 = ((1 * 4 + q4) ^ (c & 7)) * 8;

  f32x4 acc[8][4] = {};

#define STAGE_FIN(pb, kt)                                                   \
  { const u16* Ap = ((kt) < 16) ? pA1 : pA2;                                \
    const u16* Bp = ((kt) < 16) ? pB1 : pB2;                                \
    int ko = ((kt) & 15) * 64;                                              \
    _Pragma("unroll") for (int s = 0; s < 4; ++s) {                         \
      gl16(Ap + (size_t)s * 64 * 1024 + ko, As[pb] + s * 4096 + sdst);      \
      gl16(Bp + (size_t)s * 64 * 1024 + ko, Bs[pb] + s * 4096 + sdst);      \
    } }

#define COMP_FIN(pb)                                                        \
  { bf16x8 bq[4][2];                                                        \
    _Pragma("unroll") for (int j = 0; j < 4; ++j) {                         \
      int rb = (wn * 64 + j * 16 + c) * 64;                                 \
      bq[j][0] = ldb(Bs[pb] + rb + xo0);                                    \
      bq[j][1] = ldb(Bs[pb] + rb + xo1);                                    \
    }                                                                       \
    _Pragma("unroll") for (int f = 0; f < 4; ++f) {                         \
      bf16x8 aq[2][2];                                                      \
      _Pragma("unroll") for (int ii = 0; ii < 2; ++ii) {                    \
        int ra = (wm * 128 + (f * 2 + ii) * 16 + c) * 64;                   \
        aq[ii][0] = ldb(As[pb] + ra + xo0);                                 \
        aq[ii][1] = ldb(As[pb] + ra + xo1);                                 \
      }                                                                     \
      __builtin_amdgcn_s_setprio(1);                                        \
      _Pragma("unroll") for (int ii = 0; ii < 2; ++ii)                      \
        _Pragma("unroll") for (int j = 0; j < 4; ++j) {                     \
          acc[f*2+ii][j] = mfma_bf16(aq[ii][0], bq[j][0], acc[f*2+ii][j]);  \
          acc[f*2+ii][j] = mfma_bf16(aq[ii][1], bq[j][1], acc[f*2+ii][j]);  \
        }                                                                   \
      __builtin_amdgcn_s_setprio(0);                                        \
    } }

  STAGE_FIN(0, 0);
  BAR_VM0();
  for (int t = 0; t < 32; t += 2) {
    STAGE_FIN(1, t + 1);
    COMP_FIN(0);
    BAR_FULL();
    if (t + 2 < 32) STAGE_FIN(0, t + 2);
    COMP_FIN(1);
    BAR_FULL();
  }
#undef STAGE_FIN
#undef COMP_FIN

#pragma unroll
  for (int i = 0; i < 8; ++i) {
    int mrow = m0 + wm * 128 + i * 16 + q4 * 4;
#pragma unroll
    for (int j = 0; j < 4; ++j) {
      int col = n0 + wn * 64 + j * 16 + c;
      float bias = bf2f(b1[col]) + bf2f(b2[col]);
#pragma unroll
      for (int r = 0; r < 4; ++r)
        Y[(size_t)(mrow + r) * Nn + col] = acc[i][j][r] + bias;
    }
  }
}

// ---------------- LayerNorm + residual (reads raw x/ctx from d_in) -----------
__global__ __launch_bounds__(256) void ln_res(const float* Y, const u16* gamma, const u16* beta,
                                              const void* x, const void* ctx, void* out,
                                              const int* flagp) {
  int fl = *flagp;
  int row = blockIdx.x;
  int tid = threadIdx.x;
  const float* y = Y + (size_t)row * 1024;
  float4 v = *(const float4*)(y + tid * 4);
  float s  = v.x + v.y + v.z + v.w;
  float s2 = v.x * v.x + v.y * v.y + v.z * v.z + v.w * v.w;
#pragma unroll
  for (int off = 1; off < 64; off <<= 1) { s += __shfl_xor(s, off); s2 += __shfl_xor(s2, off); }
  __shared__ float red[8];
  int w = tid >> 6, lane = tid & 63;
  if (lane == 0) { red[w] = s; red[w + 4] = s2; }
  __syncthreads();
  float S  = red[0] + red[1] + red[2] + red[3];
  float S2 = red[4] + red[5] + red[6] + red[7];
  float mu  = S * (1.0f / 1024.0f);
  float var = S2 * (1.0f / 1024.0f) - mu * mu;
  float rs = rsqrtf(var + 1e-5f);
  size_t base = (size_t)row * 1024 + tid * 4;
  u16x4 gv = *(const u16x4*)(gamma + tid * 4);
  u16x4 bv = *(const u16x4*)(beta + tid * 4);
  float xr[4], cr[4];
  if (fl) {
    u16x4 xv = *(const u16x4*)((const u16*)x + base);
    u16x4 cv = *(const u16x4*)((const u16*)ctx + base);
#pragma unroll
    for (int k = 0; k < 4; ++k) { xr[k] = bf2f(xv[k]); cr[k] = bf2f(cv[k]); }
  } else {
    float4 xv = *(const float4*)((const float*)x + base);
    float4 cv = *(const float4*)((const float*)ctx + base);
    xr[0] = xv.x; xr[1] = xv.y; xr[2] = xv.z; xr[3] = xv.w;
    cr[0] = cv.x; cr[1] = cv.y; cr[2] = cv.z; cr[3] = cv.w;
  }
  float vv[4] = {v.x, v.y, v.z, v.w};
  float o[4];
#pragma unroll
  for (int k = 0; k < 4; ++k)
    o[k] = bf2f(gv[k]) * (vv[k] - mu) * rs + bf2f(bv[k]) + xr[k] + cr[k];
  if (fl) {
    u16x4 ov;
#pragma unroll
    for (int k = 0; k < 4; ++k) ov[k] = f2bf(o[k]);
    *(u16x4*)((u16*)out + base) = ov;
  } else {
    *(float4*)((float*)out + base) = make_float4(o[0], o[1], o[2], o[3]);
  }
}

// ---------------- sentinel (workspace starvation signature) ------------------
__global__ __launch_bounds__(256) void sentinel(u16* out) {
  size_t i = ((size_t)blockIdx.x * 256 + threadIdx.x) * 8;
  u16 v = f2bf(12345.0f);
  u16x8 o = {v, v, v, v, v, v, v, v};
  *(u16x8*)(out + i) = o;
}

// ---------------- host -------------------------------------------------------
extern "C" void kernel_launch(void* const* d_in, const int* in_sizes, int n_in,
                              void* d_out, int out_size, void* d_ws, size_t ws_size,
                              hipStream_t stream) {
  (void)in_sizes; (void)n_in; (void)out_size;
  const size_t MB = 1024 * 1024;
  const size_t NEED = 61 * MB;
  if (ws_size < NEED) {   // distinguishable failure signature: absmax ~12345
    sentinel<<<2048, 256, 0, stream>>>((u16*)d_out);
    return;
  }

  char* ws = (char*)d_ws;
  u16* wt[6];
  for (int i = 0; i < 6; ++i) wt[i] = (u16*)(ws + (size_t)i * 2 * MB);   // [0,12)
  u16* xc   = (u16*)(ws + 12 * MB);   // canonical bf16 x      [12,20) (dead after proj)
  u16* cc   = (u16*)(ws + 20 * MB);   // canonical bf16 ctx    [20,28) (dead after proj)
  u16* qk   = (u16*)(ws + 28 * MB);   // [28,36)
  u16* cqk  = (u16*)(ws + 36 * MB);   // [36,44)
  u16* vt   = (u16*)(ws + 44 * MB);   // [B][H][64][N]         [44,52)
  u16* cvt  = (u16*)(ws + 52 * MB);   // [52,60)
  u16* oa   = (u16*)(ws + 0);         // alias wt0-3 (dead after gemm_proj)
  u16* ca   = (u16*)(ws + 12 * MB);   // alias xc (dead after gemm_proj)
  float* y  = (float*)(ws + 28 * MB); // alias qk+cqk (dead after flash), 16MB
  int* flag = (int*)(ws + 60 * MB);
  u16* b1c  = (u16*)(ws + 60 * MB + 4096);
  u16* b2c  = (u16*)(ws + 60 * MB + 8192);
  u16* gc   = (u16*)(ws + 60 * MB + 12288);
  u16* bc   = (u16*)(ws + 60 * MB + 16384);

  detect_dtype<<<1, 256, 0, stream>>>((const u16*)d_in[0], flag);

  Cv2 cv;
  cv.s[0] = d_in[0]; cv.d[0] = xc;
  cv.s[1] = d_in[1]; cv.d[1] = cc;
  convert_big<<<dim3(2048, 1, 2), 256, 0, stream>>>(cv, flag);

  Sm4 sm;
  sm.s[0] = d_in[7]; sm.d[0] = b1c;   // b_out
  sm.s[1] = d_in[9]; sm.d[1] = b2c;   // b_cout
  sm.s[2] = d_in[10]; sm.d[2] = gc;   // gamma
  sm.s[3] = d_in[11]; sm.d[3] = bc;   // beta
  convert_smalls<<<4, 256, 0, stream>>>(sm, flag);

  T6 t;
  t.s[0] = d_in[2]; t.d[0] = wt[0];  // W_qk
  t.s[1] = d_in[3]; t.d[1] = wt[1];  // W_cqk
  t.s[2] = d_in[4]; t.d[2] = wt[2];  // W_v
  t.s[3] = d_in[5]; t.d[3] = wt[3];  // W_cv
  t.s[4] = d_in[6]; t.d[4] = wt[4];  // W_out
  t.s[5] = d_in[8]; t.d[5] = wt[5];  // W_cout
  transpose6<<<dim3(32, 32, 6), 256, 0, stream>>>(t, flag);

  Proj4 p;
  p.A[0] = xc; p.Bt[0] = wt[0]; p.C[0] = qk;  p.mode[0] = 0;
  p.A[1] = cc; p.Bt[1] = wt[1]; p.C[1] = cqk; p.mode[1] = 0;
  p.A[2] = xc; p.Bt[2] = wt[2]; p.C[2] = vt;  p.mode[2] = 1;
  p.A[3] = cc; p.Bt[3] = wt[3]; p.C[3] = cvt; p.mode[3] = 1;
  gemm_proj<<<dim3(4, 16, 4), 512, 0, stream>>>(p);

  FAz fa;
  fa.Q[0] = qk;  fa.Kp[0] = cqk; fa.Vp[0] = cvt; fa.O[0] = oa;   // out
  fa.Q[1] = cqk; fa.Kp[1] = qk;  fa.Vp[1] = vt;  fa.O[1] = ca;   // context_out
  flash_attn<<<dim3(512), 256, 0, stream>>>(fa);

  gemm_final<<<dim3(4, 16), 512, 0, stream>>>(oa, wt[4], ca, wt[5], b1c, b2c, y);

  ln_res<<<4096, 256, 0, stream>>>(y, gc, bc, d_in[0], d_in[1], d_out, flag);
}

// Round 9
// 253.935 us; speedup vs baseline: 1.1142x; 1.1142x over previous
//
#include <hip/hip_runtime.h>
#include <hip/hip_bf16.h>

typedef unsigned short u16;
typedef __bf16 bf16x8 __attribute__((ext_vector_type(8)));
typedef float   f32x4 __attribute__((ext_vector_type(4)));
typedef u16     u16x8 __attribute__((ext_vector_type(8)));
typedef u16     u16x4 __attribute__((ext_vector_type(4)));

#define DEV static __device__ __forceinline__

DEV float bf2f(u16 b) { unsigned int u = ((unsigned int)b) << 16; return __builtin_bit_cast(float, u); }
DEV u16   f2bf(float f) { return __builtin_bit_cast(u16, (__bf16)f); }
DEV bf16x8 ldb(const u16* p) { return __builtin_bit_cast(bf16x8, *(const u16x8*)p); }

DEV f32x4 mfma_bf16(bf16x8 a, bf16x8 b, f32x4 c) {
  return __builtin_amdgcn_mfma_f32_16x16x32_bf16(a, b, c, 0, 0, 0);
}

// async global->LDS, 16B per lane. LDS dest must be wave-uniform (HW adds lane*16).
DEV void gl16(const u16* g, u16* l) {
  __builtin_amdgcn_global_load_lds((const __attribute__((address_space(1))) unsigned int*)g,
                                   (__attribute__((address_space(3))) unsigned int*)l,
                                   16, 0, 0);
}

#define BAR_VM4()  asm volatile("s_waitcnt vmcnt(4)\ns_barrier" ::: "memory")
#define BAR_VM0()  asm volatile("s_waitcnt vmcnt(0)\ns_barrier" ::: "memory")
#define BAR_LG()   asm volatile("s_waitcnt lgkmcnt(0)\ns_barrier" ::: "memory")
#define BAR_FULL() asm volatile("s_waitcnt vmcnt(0) lgkmcnt(0)\ns_barrier" ::: "memory")

// ---------------- dtype detection -------------------------------------------
__global__ __launch_bounds__(256) void detect_dtype(const u16* x, int* flag) {
  int tid = threadIdx.x;
  u16 lo = x[tid * 2];
  float v = bf2f(lo);
  float av = fabsf(v);
  bool plaus = (av > 1e-4f && av < 50.f);
  __shared__ int cnt;
  if (tid == 0) cnt = 0;
  __syncthreads();
  if (plaus) atomicAdd(&cnt, 1);
  __syncthreads();
  if (tid == 0) *flag = (cnt >= 128) ? 1 : 0;   // 1 = bf16 inputs
}

// ---------------- input canonicalization to bf16 ------------------------------
struct Cv2 { const void* s[2]; u16* d[2]; };
__global__ __launch_bounds__(256) void convert_big(Cv2 p, const int* flagp) {
  int fl = *flagp;
  const void* src = p.s[blockIdx.z];
  u16* dst = p.d[blockIdx.z];
  size_t i = ((size_t)blockIdx.x * 256 + threadIdx.x) * 8;
  if (fl) {
    *(u16x8*)(dst + i) = *(const u16x8*)((const u16*)src + i);
  } else {
    const float* s = (const float*)src + i;
    u16x8 o;
#pragma unroll
    for (int k = 0; k < 8; ++k) o[k] = f2bf(s[k]);
    *(u16x8*)(dst + i) = o;
  }
}

struct Sm4 { const void* s[4]; u16* d[4]; };
__global__ __launch_bounds__(256) void convert_smalls(Sm4 p, const int* flagp) {
  int fl = *flagp;
  const void* src = p.s[blockIdx.x];
  u16* dst = p.d[blockIdx.x];
  int i = threadIdx.x * 4;
#pragma unroll
  for (int k = 0; k < 4; ++k)
    dst[i + k] = fl ? ((const u16*)src)[i + k] : f2bf(((const float*)src)[i + k]);
}

// ---------------- weight transpose: dst[n][k] = src[k][n], 1024x1024 ---------
// 64x64 tiles, fully coalesced global access. Load: u16x8 per lane (8 lanes x
// 16B = 128B line). LDS: logical tile[srccol][srcrow] stored with row-XOR
// (phys_r = rl ^ ((cl>>3)<<3), stride 72): scalar b16 scatter writes hit all
// 32 banks (bank = 36k + 4*(l&7) + ((l>>3)>>1), pair-merged words). Read side:
// XOR folds into chunk index -> contiguous u16x8 reads; store coalesced.
struct T6 { const void* s[6]; u16* d[6]; };

__global__ __launch_bounds__(256) void transpose6(T6 t, const int* flagp) {
  int fl = *flagp;
  __shared__ u16 tile[64 * 72];
  const void* src = t.s[blockIdx.z];
  u16* dst = t.d[blockIdx.z];
  int x0 = blockIdx.x * 64, y0 = blockIdx.y * 64;
  int tid = threadIdx.x;
  int r8 = tid >> 3, ch = tid & 7;

#pragma unroll
  for (int half = 0; half < 2; ++half) {
    int rl = r8 + half * 32;                      // source row within tile
    size_t si = (size_t)(y0 + rl) * 1024 + x0 + ch * 8;
    u16x8 v;
    if (fl) {
      v = *(const u16x8*)((const u16*)src + si);
    } else {
      const float* s = (const float*)src + si;
      float4 a = *(const float4*)s, b2 = *(const float4*)(s + 4);
      v[0]=f2bf(a.x); v[1]=f2bf(a.y); v[2]=f2bf(a.z); v[3]=f2bf(a.w);
      v[4]=f2bf(b2.x); v[5]=f2bf(b2.y); v[6]=f2bf(b2.z); v[7]=f2bf(b2.w);
    }
    int pr = rl ^ (ch << 3);                      // row-XOR (cl>>3 == ch)
#pragma unroll
    for (int k = 0; k < 8; ++k)
      tile[(ch * 8 + k) * 72 + pr] = v[k];
  }
  __syncthreads();
#pragma unroll
  for (int half = 0; half < 2; ++half) {
    int dr = r8 + half * 32;                      // dst row within tile
    int pch = ch ^ ((dr >> 3) & 7);               // XOR-folded chunk
    u16x8 v = *(const u16x8*)(tile + dr * 72 + pch * 8);
    *(u16x8*)(dst + (size_t)(x0 + dr) * 1024 + y0 + ch * 8) = v;
  }
}

// ---------------- projection GEMM, 256x256 tile / BK=64 / 8 waves ------------
struct Proj4 { const u16* A[4]; const u16* Bt[4]; u16* C[4]; int mode[4]; };

__global__ __launch_bounds__(512, 2) void gemm_proj(Proj4 p) {
  const int K = 1024, Nn = 1024;
  const u16* A  = p.A[blockIdx.z];
  const u16* Bt = p.Bt[blockIdx.z];
  u16* C = p.C[blockIdx.z];
  int mode = p.mode[blockIdx.z];

  __shared__ __align__(16) u16 As[2][256 * 64];
  __shared__ __align__(16) u16 Bs[2][256 * 64];

  int tid = threadIdx.x, lane = tid & 63, w = tid >> 6;
  int wm = w >> 2, wn = w & 3;          // 2 x 4 wave grid, wave tile 128x64
  int q4 = lane >> 4, c = lane & 15;

  // XCD swizzle within slice: 64 wgs, 64%8==0 -> bijective
  int bid = blockIdx.y * 4 + blockIdx.x;
  int wg  = (bid & 7) * 8 + (bid >> 3);
  int m0 = (wg >> 2) * 256, n0 = (wg & 3) * 256;

  int srow = w * 8 + (lane >> 3);
  int scol = ((lane & 7) ^ (lane >> 3)) * 8;
  const u16* pAg = A  + (size_t)(m0 + srow) * K + scol;
  const u16* pBg = Bt + (size_t)(n0 + srow) * K + scol;
  int sdst = (w * 8) * 64;

  int xo0 = ((0 * 4 + q4) ^ (c & 7)) * 8;
  int xo1 = ((1 * 4 + q4) ^ (c & 7)) * 8;

  f32x4 acc[8][4] = {};

#define STAGE256(pb, kt)                                                    \
  { int ko = (kt) * 64;                                                     \
    _Pragma("unroll") for (int s = 0; s < 4; ++s) {                         \
      gl16(pAg + (size_t)s * 64 * 1024 + ko, As[pb] + s * 4096 + sdst);     \
      gl16(pBg + (size_t)s * 64 * 1024 + ko, Bs[pb] + s * 4096 + sdst);     \
    } }

#define COMP256(pb)                                                         \
  { bf16x8 bq[4][2];                                                        \
    _Pragma("unroll") for (int j = 0; j < 4; ++j) {                         \
      int rb = (wn * 64 + j * 16 + c) * 64;                                 \
      bq[j][0] = ldb(Bs[pb] + rb + xo0);                                    \
      bq[j][1] = ldb(Bs[pb] + rb + xo1);                                    \
    }                                                                       \
    _Pragma("unroll") for (int f = 0; f < 4; ++f) {                         \
      bf16x8 aq[2][2];                                                      \
      _Pragma("unroll") for (int ii = 0; ii < 2; ++ii) {                    \
        int ra = (wm * 128 + (f * 2 + ii) * 16 + c) * 64;                   \
        aq[ii][0] = ldb(As[pb] + ra + xo0);                                 \
        aq[ii][1] = ldb(As[pb] + ra + xo1);                                 \
      }                                                                     \
      __builtin_amdgcn_s_setprio(1);                                        \
      _Pragma("unroll") for (int ii = 0; ii < 2; ++ii)                      \
        _Pragma("unroll") for (int j = 0; j < 4; ++j) {                     \
          acc[f*2+ii][j] = mfma_bf16(aq[ii][0], bq[j][0], acc[f*2+ii][j]);  \
          acc[f*2+ii][j] = mfma_bf16(aq[ii][1], bq[j][1], acc[f*2+ii][j]);  \
        }                                                                   \
      __builtin_amdgcn_s_setprio(0);                                        \
    } }

  STAGE256(0, 0);
  BAR_VM0();
  for (int t = 0; t < 16; t += 2) {
    STAGE256(1, t + 1);
    COMP256(0);
    BAR_FULL();
    if (t + 2 < 16) STAGE256(0, t + 2);
    COMP256(1);
    BAR_FULL();
  }
#undef STAGE256
#undef COMP256

  if (mode == 0) {
#pragma unroll
    for (int i = 0; i < 8; ++i) {
      int mrow = m0 + wm * 128 + i * 16 + q4 * 4;
#pragma unroll
      for (int j = 0; j < 4; ++j) {
        int col = n0 + wn * 64 + j * 16 + c;
#pragma unroll
        for (int r = 0; r < 4; ++r)
          C[(size_t)(mrow + r) * Nn + col] = f2bf(acc[i][j][r]);
      }
    }
  } else {
    int bidx = m0 >> 10;
#pragma unroll
    for (int i = 0; i < 8; ++i) {
      int mrow = m0 + wm * 128 + i * 16 + q4 * 4;
      int jj = mrow & 1023;
#pragma unroll
      for (int j = 0; j < 4; ++j) {
        int col = n0 + wn * 64 + j * 16 + c;
        int h = col >> 6, dh = col & 63;
        u16x4 pk;
#pragma unroll
        for (int r = 0; r < 4; ++r) pk[r] = f2bf(acc[i][j][r]);
        *(u16x4*)(C + ((size_t)((bidx * 16 + h) * 64 + dh)) * 1024 + jj) = pk;
      }
    }
  }
}

// ---------------- flash attention (max-free, S^T orientation) ----------------
// Round-6 proven config: 1024 blocks, 128 Q-rows/block (2 i-groups/wave).
// XCD decode: the 8 i-blocks sharing one (bh,z) K/V panel have equal flat%8
// -> same XCD L2. K/V LDS chunk-XOR swizzled; softmax = single exp2 per elem.
struct FAz { const u16* Q[2]; const u16* Kp[2]; const u16* Vp[2]; u16* O[2]; };

__global__ __launch_bounds__(256) void flash_attn(FAz fa) {
  int flat = blockIdx.x;
  int i0 = (flat >> 7) * 128;
  int grp = flat & 127;
  int z = grp >> 6;
  int bh = grp & 63;
  const u16* Q  = fa.Q[z];
  const u16* Kg = fa.Kp[z];
  const u16* Vt = fa.Vp[z];
  u16* O = fa.O[z];

  int b = bh >> 4, h = bh & 15;
  int tid = threadIdx.x, lane = tid & 63, w = tid >> 6;
  int q4 = lane >> 4, c = lane & 15;

  __shared__ __align__(16) u16 Ks[64 * 64];       // [j][d] chunk-XOR swizzled
  __shared__ __align__(16) u16 Vs[64 * 64];       // [d][j] chunk-XOR swizzled
  __shared__ __align__(16) u16 Ps[4][2][16 * 72]; // per-wave, per-group P [i][j]

  bf16x8 qf[2][2];
#pragma unroll
  for (int g = 0; g < 2; ++g) {
    const size_t qoff = ((size_t)(b * 1024 + i0 + g * 64 + w * 16 + c)) * 1024 + h * 64 + q4 * 8;
    qf[g][0] = ldb(Q + qoff);
    qf[g][1] = ldb(Q + qoff + 32);
  }

  f32x4 of[2][4] = {};
  f32x4 lacc[2] = {};
  bf16x8 ones;
#pragma unroll
  for (int k = 0; k < 8; ++k) ones[k] = (__bf16)1.0f;

  int jr = tid >> 2, seg = (tid & 3) * 16;
  const u16* krow_base = Kg + ((size_t)(b * 1024 + jr)) * 1024 + h * 64 + seg;
  const u16* vrow_base = Vt + ((size_t)((b * 16 + h) * 64 + jr)) * 1024 + seg;

  // swizzled LDS write addresses for this lane's two 16B chunks
  int ch0 = (tid & 3) * 2, jrx = jr & 7;
  int wa0 = jr * 64 + ((ch0)     ^ jrx) * 8;
  int wa1 = jr * 64 + ((ch0 + 1) ^ jrx) * 8;
  // swizzled read offsets (per-thread constants)
  int xA = (q4 ^ (c & 7)) * 8;
  int xB = xA ^ 32;

  const float C2 = 0.125f * 1.4426950408889634f;  // scale * log2(e)

  u16x8 kv0 = *(const u16x8*)(krow_base);
  u16x8 kv1 = *(const u16x8*)(krow_base + 8);
  u16x8 vv0 = *(const u16x8*)(vrow_base);
  u16x8 vv1 = *(const u16x8*)(vrow_base + 8);

  for (int j0 = 0; j0 < 1024; j0 += 64) {
    __syncthreads();
    *(u16x8*)(Ks + wa0) = kv0;
    *(u16x8*)(Ks + wa1) = kv1;
    *(u16x8*)(Vs + wa0) = vv0;
    *(u16x8*)(Vs + wa1) = vv1;
    __syncthreads();

    if (j0 + 64 < 1024) {
      const u16* ks = krow_base + (size_t)(j0 + 64) * 1024;
      kv0 = *(const u16x8*)(ks);
      kv1 = *(const u16x8*)(ks + 8);
      const u16* vs = vrow_base + j0 + 64;
      vv0 = *(const u16x8*)(vs);
      vv1 = *(const u16x8*)(vs + 8);
    }

    f32x4 sf[2][4] = {};
    __builtin_amdgcn_s_setprio(1);
#pragma unroll
    for (int jc = 0; jc < 4; ++jc) {
      int rk = (jc * 16 + c) * 64;
      bf16x8 k0f = ldb(Ks + rk + xA);
      bf16x8 k1f = ldb(Ks + rk + xB);
#pragma unroll
      for (int g = 0; g < 2; ++g) {
        sf[g][jc] = mfma_bf16(k0f, qf[g][0], sf[g][jc]);
        sf[g][jc] = mfma_bf16(k1f, qf[g][1], sf[g][jc]);
      }
    }
    __builtin_amdgcn_s_setprio(0);

#pragma unroll
    for (int g = 0; g < 2; ++g)
#pragma unroll
      for (int jc = 0; jc < 4; ++jc) {
        u16x4 pk;
#pragma unroll
        for (int r = 0; r < 4; ++r)
          pk[r] = f2bf(__builtin_amdgcn_exp2f(sf[g][jc][r] * C2));
        *(u16x4*)(Ps[w][g] + c * 72 + jc * 16 + q4 * 4) = pk;
      }

    asm volatile("s_waitcnt lgkmcnt(0)" ::: "memory");

    bf16x8 pf[2][2];
#pragma unroll
    for (int g = 0; g < 2; ++g) {
      pf[g][0] = ldb(Ps[w][g] + c * 72 + q4 * 8);
      pf[g][1] = ldb(Ps[w][g] + c * 72 + 32 + q4 * 8);
      lacc[g] = mfma_bf16(pf[g][0], ones, lacc[g]);
      lacc[g] = mfma_bf16(pf[g][1], ones, lacc[g]);
    }

    __builtin_amdgcn_s_setprio(1);
#pragma unroll
    for (int dc = 0; dc < 4; ++dc) {
      int rv = (dc * 16 + c) * 64;
      bf16x8 v0f = ldb(Vs + rv + xA);
      bf16x8 v1f = ldb(Vs + rv + xB);
#pragma unroll
      for (int g = 0; g < 2; ++g) {
        of[g][dc] = mfma_bf16(pf[g][0], v0f, of[g][dc]);
        of[g][dc] = mfma_bf16(pf[g][1], v1f, of[g][dc]);
      }
    }
    __builtin_amdgcn_s_setprio(0);
  }

#pragma unroll
  for (int g = 0; g < 2; ++g) {
    float inv[4];
#pragma unroll
    for (int r = 0; r < 4; ++r) inv[r] = 1.0f / lacc[g][r];
#pragma unroll
    for (int dc = 0; dc < 4; ++dc) {
      int col = h * 64 + dc * 16 + c;
#pragma unroll
      for (int r = 0; r < 4; ++r) {
        int irow = i0 + g * 64 + w * 16 + q4 * 4 + r;
        O[((size_t)(b * 1024 + irow)) * 1024 + col] = f2bf(of[g][dc][r] * inv[r]);
      }
    }
  }
}

// ---------------- final dual GEMM + bias -> fp32 (128^2, counted vmcnt) ------
// 256 blocks (full machine). 64 K-steps of 32: kk<32 reads (A1,B1), else
// (A2,B2) -- covers both full K=1024 ranges.
__global__ __launch_bounds__(256) void gemm_final(const u16* A1, const u16* B1t,
                                                  const u16* A2, const u16* B2t,
                                                  const u16* b1, const u16* b2,
                                                  float* Y) {
  const int K = 1024, Nn = 1024;
  __shared__ __align__(16) u16 As[2][128 * 32];
  __shared__ __align__(16) u16 Bs[2][128 * 32];

  int tid = threadIdx.x, lane = tid & 63, w = tid >> 6;
  int wm = w & 1, wn = w >> 1;
  int q4 = lane >> 4, c = lane & 15;

  int bid = blockIdx.y * 8 + blockIdx.x;
  int wg  = (bid & 7) * 32 + (bid >> 3);
  int m0 = (wg >> 3) * 128, n0 = (wg & 7) * 128;

  int r0 = w * 32 + (lane >> 2);
  int cc = (lane & 3) ^ ((lane >> 3) & 3);
  const u16* A1p = A1  + (size_t)(m0 + r0) * K + cc * 8;
  const u16* A2p = A2  + (size_t)(m0 + r0) * K + cc * 8;
  const u16* B1p = B1t + (size_t)(n0 + r0) * K + cc * 8;
  const u16* B2p = B2t + (size_t)(n0 + r0) * K + cc * 8;
  int qs = (q4 ^ ((c >> 1) & 3)) * 8;

  f32x4 acc[4][4] = {};

#define STAGE_F(buf, kk)                                          \
  { const u16* Ap = ((kk) < 32) ? A1p : A2p;                      \
    const u16* Bp = ((kk) < 32) ? B1p : B2p;                      \
    int k0_ = ((kk) & 31) * 32;                                   \
    gl16(Ap + k0_,          As[buf] + w * 1024);                  \
    gl16(Ap + 16 * K + k0_, As[buf] + w * 1024 + 512);            \
    gl16(Bp + k0_,          Bs[buf] + w * 1024);                  \
    gl16(Bp + 16 * K + k0_, Bs[buf] + w * 1024 + 512); }

#define COMP_F(buf)                                               \
  { bf16x8 af[4], bfr[4];                                         \
    _Pragma("unroll") for (int i = 0; i < 4; ++i)                 \
      af[i]  = ldb(As[buf] + (wm * 64 + i * 16 + c) * 32 + qs);   \
    _Pragma("unroll") for (int j = 0; j < 4; ++j)                 \
      bfr[j] = ldb(Bs[buf] + (wn * 64 + j * 16 + c) * 32 + qs);   \
    _Pragma("unroll") for (int i = 0; i < 4; ++i)                 \
      _Pragma("unroll") for (int j = 0; j < 4; ++j)               \
        acc[i][j] = mfma_bf16(af[i], bfr[j], acc[i][j]); }

  STAGE_F(0, 0);
  for (int t = 0; t < 62; t += 2) {
    STAGE_F(1, t + 1);
    BAR_VM4();
    COMP_F(0);
    BAR_LG();
    STAGE_F(0, t + 2);
    BAR_VM4();
    COMP_F(1);
    BAR_LG();
  }
  STAGE_F(1, 63);
  BAR_VM4();
  COMP_F(0);
  BAR_LG();
  BAR_VM0();
  COMP_F(1);
#undef STAGE_F
#undef COMP_F

#pragma unroll
  for (int i = 0; i < 4; ++i) {
    int mrow = m0 + wm * 64 + i * 16 + q4 * 4;
#pragma unroll
    for (int j = 0; j < 4; ++j) {
      int col = n0 + wn * 64 + j * 16 + c;
      float bias = bf2f(b1[col]) + bf2f(b2[col]);
#pragma unroll
      for (int r = 0; r < 4; ++r)
        Y[(size_t)(mrow + r) * Nn + col] = acc[i][j][r] + bias;
    }
  }
}

// ---------------- LayerNorm + residual (reads raw x/ctx from d_in) -----------
__global__ __launch_bounds__(256) void ln_res(const float* Y, const u16* gamma, const u16* beta,
                                              const void* x, const void* ctx, void* out,
                                              const int* flagp) {
  int fl = *flagp;
  int row = blockIdx.x;
  int tid = threadIdx.x;
  const float* y = Y + (size_t)row * 1024;
  float4 v = *(const float4*)(y + tid * 4);
  float s  = v.x + v.y + v.z + v.w;
  float s2 = v.x * v.x + v.y * v.y + v.z * v.z + v.w * v.w;
#pragma unroll
  for (int off = 1; off < 64; off <<= 1) { s += __shfl_xor(s, off); s2 += __shfl_xor(s2, off); }
  __shared__ float red[8];
  int w = tid >> 6, lane = tid & 63;
  if (lane == 0) { red[w] = s; red[w + 4] = s2; }
  __syncthreads();
  float S  = red[0] + red[1] + red[2] + red[3];
  float S2 = red[4] + red[5] + red[6] + red[7];
  float mu  = S * (1.0f / 1024.0f);
  float var = S2 * (1.0f / 1024.0f) - mu * mu;
  float rs = rsqrtf(var + 1e-5f);
  size_t base = (size_t)row * 1024 + tid * 4;
  u16x4 gv = *(const u16x4*)(gamma + tid * 4);
  u16x4 bv = *(const u16x4*)(beta + tid * 4);
  float xr[4], cr[4];
  if (fl) {
    u16x4 xv = *(const u16x4*)((const u16*)x + base);
    u16x4 cv = *(const u16x4*)((const u16*)ctx + base);
#pragma unroll
    for (int k = 0; k < 4; ++k) { xr[k] = bf2f(xv[k]); cr[k] = bf2f(cv[k]); }
  } else {
    float4 xv = *(const float4*)((const float*)x + base);
    float4 cv = *(const float4*)((const float*)ctx + base);
    xr[0] = xv.x; xr[1] = xv.y; xr[2] = xv.z; xr[3] = xv.w;
    cr[0] = cv.x; cr[1] = cv.y; cr[2] = cv.z; cr[3] = cv.w;
  }
  float vv[4] = {v.x, v.y, v.z, v.w};
  float o[4];
#pragma unroll
  for (int k = 0; k < 4; ++k)
    o[k] = bf2f(gv[k]) * (vv[k] - mu) * rs + bf2f(bv[k]) + xr[k] + cr[k];
  if (fl) {
    u16x4 ov;
#pragma unroll
    for (int k = 0; k < 4; ++k) ov[k] = f2bf(o[k]);
    *(u16x4*)((u16*)out + base) = ov;
  } else {
    *(float4*)((float*)out + base) = make_float4(o[0], o[1], o[2], o[3]);
  }
}

// ---------------- sentinel (workspace starvation signature) ------------------
__global__ __launch_bounds__(256) void sentinel(u16* out) {
  size_t i = ((size_t)blockIdx.x * 256 + threadIdx.x) * 8;
  u16 v = f2bf(12345.0f);
  u16x8 o = {v, v, v, v, v, v, v, v};
  *(u16x8*)(out + i) = o;
}

// ---------------- host -------------------------------------------------------
extern "C" void kernel_launch(void* const* d_in, const int* in_sizes, int n_in,
                              void* d_out, int out_size, void* d_ws, size_t ws_size,
                              hipStream_t stream) {
  (void)in_sizes; (void)n_in; (void)out_size;
  const size_t MB = 1024 * 1024;
  const size_t NEED = 61 * MB;
  if (ws_size < NEED) {   // distinguishable failure signature: absmax ~12345
    sentinel<<<2048, 256, 0, stream>>>((u16*)d_out);
    return;
  }

  char* ws = (char*)d_ws;
  u16* wt[6];
  for (int i = 0; i < 6; ++i) wt[i] = (u16*)(ws + (size_t)i * 2 * MB);   // [0,12)
  u16* xc   = (u16*)(ws + 12 * MB);   // canonical bf16 x      [12,20) (dead after proj)
  u16* cc   = (u16*)(ws + 20 * MB);   // canonical bf16 ctx    [20,28) (dead after proj)
  u16* qk   = (u16*)(ws + 28 * MB);   // [28,36)
  u16* cqk  = (u16*)(ws + 36 * MB);   // [36,44)
  u16* vt   = (u16*)(ws + 44 * MB);   // [B][H][64][N]         [44,52)
  u16* cvt  = (u16*)(ws + 52 * MB);   // [52,60)
  u16* oa   = (u16*)(ws + 0);         // alias wt0-3 (dead after gemm_proj)
  u16* ca   = (u16*)(ws + 12 * MB);   // alias xc (dead after gemm_proj)
  float* y  = (float*)(ws + 28 * MB); // alias qk+cqk (dead after flash), 16MB
  int* flag = (int*)(ws + 60 * MB);
  u16* b1c  = (u16*)(ws + 60 * MB + 4096);
  u16* b2c  = (u16*)(ws + 60 * MB + 8192);
  u16* gc   = (u16*)(ws + 60 * MB + 12288);
  u16* bc   = (u16*)(ws + 60 * MB + 16384);

  detect_dtype<<<1, 256, 0, stream>>>((const u16*)d_in[0], flag);

  Cv2 cv;
  cv.s[0] = d_in[0]; cv.d[0] = xc;
  cv.s[1] = d_in[1]; cv.d[1] = cc;
  convert_big<<<dim3(2048, 1, 2), 256, 0, stream>>>(cv, flag);

  Sm4 sm;
  sm.s[0] = d_in[7]; sm.d[0] = b1c;   // b_out
  sm.s[1] = d_in[9]; sm.d[1] = b2c;   // b_cout
  sm.s[2] = d_in[10]; sm.d[2] = gc;   // gamma
  sm.s[3] = d_in[11]; sm.d[3] = bc;   // beta
  convert_smalls<<<4, 256, 0, stream>>>(sm, flag);

  T6 t;
  t.s[0] = d_in[2]; t.d[0] = wt[0];  // W_qk
  t.s[1] = d_in[3]; t.d[1] = wt[1];  // W_cqk
  t.s[2] = d_in[4]; t.d[2] = wt[2];  // W_v
  t.s[3] = d_in[5]; t.d[3] = wt[3];  // W_cv
  t.s[4] = d_in[6]; t.d[4] = wt[4];  // W_out
  t.s[5] = d_in[8]; t.d[5] = wt[5];  // W_cout
  transpose6<<<dim3(16, 16, 6), 256, 0, stream>>>(t, flag);

  Proj4 p;
  p.A[0] = xc; p.Bt[0] = wt[0]; p.C[0] = qk;  p.mode[0] = 0;
  p.A[1] = cc; p.Bt[1] = wt[1]; p.C[1] = cqk; p.mode[1] = 0;
  p.A[2] = xc; p.Bt[2] = wt[2]; p.C[2] = vt;  p.mode[2] = 1;
  p.A[3] = cc; p.Bt[3] = wt[3]; p.C[3] = cvt; p.mode[3] = 1;
  gemm_proj<<<dim3(4, 16, 4), 512, 0, stream>>>(p);

  FAz fa;
  fa.Q[0] = qk;  fa.Kp[0] = cqk; fa.Vp[0] = cvt; fa.O[0] = oa;   // out
  fa.Q[1] = cqk; fa.Kp[1] = qk;  fa.Vp[1] = vt;  fa.O[1] = ca;   // context_out
  flash_attn<<<dim3(1024), 256, 0, stream>>>(fa);

  gemm_final<<<dim3(8, 32), 256, 0, stream>>>(oa, wt[4], ca, wt[5], b1c, b2c, y);

  ln_res<<<4096, 256, 0, stream>>>(y, gc, bc, d_in[0], d_in[1], d_out, flag);
}